// Round 1
// 137.297 us; speedup vs baseline: 1.0030x; 1.0030x over previous
//
#include <hip/hip_runtime.h>

// BilinearPooling: out[i,k] = mean_j(conv1[i,j]) * conv2[i,k]
// B=256, J=K=14*14*256=50176. Memory-bound: 154 MB min HBM traffic (~25 us floor).
//
// Two streaming kernels, workspace handoff (no atomics, deterministic):
//   A: 1792 blocks x 256 thr, each reduces a 1792-float4 segment -> d_ws[blk]
//   B: 1792 blocks x 256 thr, each sums its row's 7 partials, scales conv2 segment.
// 7 blocks/row * 4 waves = up to 28 waves/CU across 7 blocks -> deep MLP, no
// per-block phase barrier serializing the two streams.

#define ROW_ELEMS 50176            // 14*14*256
#define ROW_VEC   12544            // float4 per row
#define BLOCKS_PER_ROW 7
#define SEG_VEC   (ROW_VEC / BLOCKS_PER_ROW)   // 1792 float4 per block
#define THREADS   256
#define ITERS     (SEG_VEC / THREADS)          // 7 exact, no bounds check

__global__ __launch_bounds__(THREADS)
void bp_reduce_kernel(const float4* __restrict__ c1, float* __restrict__ partials) {
    const int row = blockIdx.x / BLOCKS_PER_ROW;
    const int seg = blockIdx.x % BLOCKS_PER_ROW;
    const float4* __restrict__ p =
        c1 + (size_t)row * ROW_VEC + (size_t)seg * SEG_VEC + threadIdx.x;

    // 7 independent float4 loads -> 7 in flight per wave before the adds need them.
    float s = 0.0f;
    #pragma unroll
    for (int i = 0; i < ITERS; ++i) {
        float4 v = p[i * THREADS];
        s += (v.x + v.y) + (v.z + v.w);
    }

    // wave-64 butterfly, then 4-wave LDS combine
    #pragma unroll
    for (int off = 32; off > 0; off >>= 1)
        s += __shfl_down(s, off, 64);

    __shared__ float wsum[THREADS / 64];
    const int lane = threadIdx.x & 63;
    const int wid  = threadIdx.x >> 6;
    if (lane == 0) wsum[wid] = s;
    __syncthreads();
    if (threadIdx.x == 0) {
        partials[blockIdx.x] = (wsum[0] + wsum[1]) + (wsum[2] + wsum[3]);
    }
}

__global__ __launch_bounds__(THREADS)
void bp_scale_kernel(const float4* __restrict__ c2,
                     const float* __restrict__ partials,
                     float4* __restrict__ out) {
    const int row = blockIdx.x / BLOCKS_PER_ROW;
    const int seg = blockIdx.x % BLOCKS_PER_ROW;

    // 28 B of partials per row; block-uniform address, L2-hot.
    const float* pr = partials + row * BLOCKS_PER_ROW;
    float t = 0.0f;
    #pragma unroll
    for (int i = 0; i < BLOCKS_PER_ROW; ++i) t += pr[i];
    const float m = t * (1.0f / (float)ROW_ELEMS);

    const size_t base = (size_t)row * ROW_VEC + (size_t)seg * SEG_VEC + threadIdx.x;
    const float4* __restrict__ p = c2 + base;
    float4* __restrict__ o = out + base;

    #pragma unroll
    for (int i = 0; i < ITERS; ++i) {
        float4 v = p[i * THREADS];
        v.x *= m; v.y *= m; v.z *= m; v.w *= m;
        o[i * THREADS] = v;
    }
}

extern "C" void kernel_launch(void* const* d_in, const int* in_sizes, int n_in,
                              void* d_out, int out_size, void* d_ws, size_t ws_size,
                              hipStream_t stream) {
    const float4* c1 = (const float4*)d_in[0];
    const float4* c2 = (const float4*)d_in[1];
    float4* out = (float4*)d_out;
    float* partials = (float*)d_ws;   // needs 1792*4 = 7168 B of workspace

    const int grid = 256 * BLOCKS_PER_ROW;  // 1792
    bp_reduce_kernel<<<grid, THREADS, 0, stream>>>(c1, partials);
    bp_scale_kernel<<<grid, THREADS, 0, stream>>>(c2, partials, out);
}